// Round 6
// baseline (241.727 us; speedup 1.0000x reference)
//
#include <hip/hip_runtime.h>
#include <cstdint>
#include <cstddef>

typedef unsigned int u32;
typedef unsigned short u16;
typedef __attribute__((ext_vector_type(8))) short short8;   // 8 bf16 = 4 VGPRs (MFMA A/B frag)
typedef __attribute__((ext_vector_type(4))) float f32x4;    // MFMA C/D frag

#define S_LEN 1024
#define BATCH 16
#define NHEAD 8
#define DMODEL 512
#define KHD 64
#define NROW (S_LEN * BATCH)          // 16384 GEMM rows

__device__ __forceinline__ u16 f2bf(float f) {
    u32 u = __float_as_uint(f);
    return (u16)((u + 0x7fffu + ((u >> 16) & 1u)) >> 16);   // RTNE
}

__device__ __forceinline__ void gl_lds16(const void* g, void* l) {
    __builtin_amdgcn_global_load_lds(
        (const __attribute__((address_space(1))) void*)(uintptr_t)g,
        (__attribute__((address_space(3))) void*)(uintptr_t)l, 16, 0, 0);
}

// ---------------------------------------------------------------------------
// Weights fp32 -> bf16, packed [4][512*512] into ws.
// ---------------------------------------------------------------------------
__global__ __launch_bounds__(256) void wcvt_kernel(
    const float* __restrict__ WQ, const float* __restrict__ WK,
    const float* __restrict__ WV, const float* __restrict__ Wo,
    u16* __restrict__ dst)
{
    const int m = blockIdx.y;
    const float* __restrict__ src = (m == 0) ? WQ : (m == 1) ? WK : (m == 2) ? WV : Wo;
    const int idx = (blockIdx.x * 256 + threadIdx.x) * 4;
    const float4 v = *(const float4*)(src + idx);
    u16 r[4];
    r[0] = f2bf(v.x); r[1] = f2bf(v.y); r[2] = f2bf(v.z); r[3] = f2bf(v.w);
    *(uint2*)(dst + (size_t)m * DMODEL * DMODEL + idx) = *(uint2*)r;
}

// ---------------------------------------------------------------------------
// bf16-MFMA GEMM, 128x128 tile, BK=64, DOUBLE-BUFFERED K-loop:
//   stage(next tile) BEFORE compute(cur), ONE barrier per iter -> load
//   latency hides under 32 MFMAs instead of serializing (R5 fix: old
//   structure drained vmcnt immediately after issuing loads; gemm<0>
//   measured MfmaUtil 9.7% / all pipes idle = latency-bound).
// B staged via global_load_lds width=16, XOR chunk swizzle in the GLOBAL
// address (LDS lane-contiguous).
// A staging:
//   M==0: bf16 gather from [B][H][S][64] via global_load_lds (attn concat).
//   M==1/2: FUSED fp32->bf16, T14 async split: issue global_load_dwordx4
//           early -> compute(cur) -> vmcnt wait + v_cvt_pk_bf16_f32 +
//           swizzled ds_write into Alds[nxt] -> barrier.
// M==0: fp32 out to outP.                                 grid (128,4,1)
// M==1: per-head L2 norm, bf16 out [B][H][S][64], z=q/k.  grid (128,4,2)
// M==2: per-head L2 norm, V transposed out [B][H][64][S]. grid (8,4,16)
//       A rows are consecutive s for batch bb (astr = B*D).
// LDS 64KB -> 2 blocks/CU (gemm<0> grid is 512 = 2/CU anyway).
// ---------------------------------------------------------------------------
template<int M>
__global__ __launch_bounds__(256, 2) void gemm_kernel(
    const float* __restrict__ A0,   // fp32 activation (M1: q; M2: v)
    const float* __restrict__ A1,   // fp32 activation (M1: k)
    const u16* __restrict__ Abf,    // bf16 A base (M0 only, [B][H][S][64])
    const u16* __restrict__ Wb,     // bf16 weight panel (M1: +z*D*D inside)
    u16* __restrict__ outN,
    float* __restrict__ outP)
{
    __shared__ __align__(16) u16 Alds[2][128 * 64];
    __shared__ __align__(16) u16 Blds[2][128 * 64];

    const int tid  = threadIdx.x;
    const int wave = tid >> 6;
    const int lane = tid & 63;
    const int m16  = lane & 15;
    const int quad = lane >> 4;
    const int wm   = wave >> 1;
    const int wn   = wave & 1;
    const int n0   = blockIdx.y * 128;
    const int row0 = blockIdx.x * 128;
    const int z    = (M == 1) ? blockIdx.z : 0;
    const int bb   = (M == 2) ? blockIdx.z : 0;

    // fp32 A base + row stride (elements)
    const float* __restrict__ A32 =
        (M == 1) ? (z ? A1 : A0) : (M == 2) ? (A0 + (size_t)bb * DMODEL) : nullptr;
    const size_t astr = (M == 2) ? (size_t)BATCH * DMODEL : (size_t)DMODEL;
    const u16* __restrict__ B = Wb + ((M == 1) ? (size_t)z * DMODEL * DMODEL : 0);

    f32x4 acc[4][4] = {};

    const int brow   = lane >> 3;              // 0..7
    const int bchunk = (lane & 7) ^ brow;      // XOR chunk swizzle (B / M0-A)
    const int acf    = lane & 7;               // fused path: 16B fp32 chunk

    float4 av[8];                              // next-tile fp32 A (M1/M2)

    auto stage_B = [&](int kt, int b) {
        const u16* bp = B + (size_t)(n0 + wave * 32 + brow) * DMODEL + kt + bchunk * 8;
        u16* lb = &Blds[b][(wave * 32) * 64];
#pragma unroll
        for (int j = 0; j < 4; j++)
            gl_lds16(bp + (size_t)j * 8 * DMODEL, lb + j * 8 * 64);
    };
    auto stage_A0 = [&](int kt, int b) {
        // A lives in [B][H][S][64]: row i = s*16+b, col c = h*64+kk.
        // 16B chunks never straddle a head boundary (8 | 64).
        u16* la = &Alds[b][(wave * 32) * 64];
        const int colc = kt + bchunk * 8;
        const int hh   = colc >> 6;
        const int kk   = colc & 63;
#pragma unroll
        for (int j = 0; j < 4; j++) {
            const int i  = row0 + wave * 32 + brow + j * 8;
            const int ss = i >> 4, bx = i & 15;
            gl_lds16(Abf + (((size_t)(bx * NHEAD + hh) * S_LEN + ss) * KHD + kk),
                     la + j * 8 * 64);
        }
    };
    auto load_A = [&](int kt) {
#pragma unroll
        for (int j = 0; j < 8; j++) {
            const int rl = wave * 32 + (j & 3) * 8 + brow;
            const int cf = (j >> 2) * 8 + acf;        // 0..15
            av[j] = *(const float4*)(A32 + (size_t)(row0 + rl) * astr + kt + cf * 4);
        }
    };
    auto write_A = [&](int b) {
#pragma unroll
        for (int j = 0; j < 8; j++) {
            const int rl = wave * 32 + (j & 3) * 8 + brow;
            const int cf = (j >> 2) * 8 + acf;
            u32 lo, hi;
            asm("v_cvt_pk_bf16_f32 %0, %1, %2" : "=v"(lo) : "v"(av[j].x), "v"(av[j].y));
            asm("v_cvt_pk_bf16_f32 %0, %1, %2" : "=v"(hi) : "v"(av[j].z), "v"(av[j].w));
            uint2 pk; pk.x = lo; pk.y = hi;
            // bf16 LDS layout: row rl, chunk (cf>>1)^(rl&7), half cf&1
            *(uint2*)&Alds[b][rl * 64 + (((cf >> 1) ^ (rl & 7)) << 3) + ((cf & 1) << 2)] = pk;
        }
    };
    auto compute = [&](int b) {
#pragma unroll
        for (int half = 0; half < 2; half++) {
            short8 af[4], bfr[4];
#pragma unroll
            for (int mt = 0; mt < 4; mt++)
                af[mt] = *(const short8*)&Alds[b][(wm * 64 + mt * 16 + m16) * 64 +
                                                  (((half << 2) + quad) ^ (m16 & 7)) * 8];
#pragma unroll
            for (int nt = 0; nt < 4; nt++)
                bfr[nt] = *(const short8*)&Blds[b][(wn * 64 + nt * 16 + m16) * 64 +
                                                   (((half << 2) + quad) ^ (m16 & 7)) * 8];
#pragma unroll
            for (int mt = 0; mt < 4; mt++)
#pragma unroll
                for (int nt = 0; nt < 4; nt++)
                    acc[mt][nt] = __builtin_amdgcn_mfma_f32_16x16x32_bf16(af[mt], bfr[nt], acc[mt][nt], 0, 0, 0);
        }
    };

    // prologue: fill buf 0
    if (M == 0) { stage_A0(0, 0); stage_B(0, 0); }
    else        { load_A(0); stage_B(0, 0); write_A(0); }
    __syncthreads();

#pragma unroll 2
    for (int it = 0; it < 8; it++) {
        const int cur = it & 1;
        const int nxt = cur ^ 1;
        if (it < 7) {
            if (M == 0) { stage_A0((it + 1) * 64, nxt); stage_B((it + 1) * 64, nxt); }
            else        { load_A((it + 1) * 64);        stage_B((it + 1) * 64, nxt); }
        }
        compute(cur);
        if (M != 0 && it < 7) write_A(nxt);
        __syncthreads();   // next tile visible + cur buf free for it+1 staging
    }

    if (M == 1) {
        const int h = (n0 >> 6) + wn;
        u16* outZ = outN + (size_t)z * BATCH * NHEAD * S_LEN * KHD;
#pragma unroll
        for (int mt = 0; mt < 4; mt++) {
#pragma unroll
            for (int r = 0; r < 4; r++) {
                float ss = 0.0f;
#pragma unroll
                for (int nt = 0; nt < 4; nt++) ss += acc[mt][nt][r] * acc[mt][nt][r];
                ss += __shfl_xor(ss, 1);
                ss += __shfl_xor(ss, 2);
                ss += __shfl_xor(ss, 4);
                ss += __shfl_xor(ss, 8);
                const float sc = 1.0f / fmaxf(sqrtf(ss), 1e-12f);
                const int i = row0 + wm * 64 + mt * 16 + quad * 4 + r;
                const int s = i >> 4, b = i & 15;
                u16* op = outZ + (((size_t)b * NHEAD + h) * S_LEN + s) * KHD;
#pragma unroll
                for (int nt = 0; nt < 4; nt++)
                    op[nt * 16 + m16] = f2bf(acc[mt][nt][r] * sc);
            }
        }
    } else if (M == 2) {
        const int h = (n0 >> 6) + wn;
#pragma unroll
        for (int mt = 0; mt < 4; mt++) {
            float scl[4];
#pragma unroll
            for (int r = 0; r < 4; r++) {
                float ss = 0.0f;
#pragma unroll
                for (int nt = 0; nt < 4; nt++) ss += acc[mt][nt][r] * acc[mt][nt][r];
                ss += __shfl_xor(ss, 1);
                ss += __shfl_xor(ss, 2);
                ss += __shfl_xor(ss, 4);
                ss += __shfl_xor(ss, 8);
                scl[r] = 1.0f / fmaxf(sqrtf(ss), 1e-12f);
            }
            const int sbase = row0 + wm * 64 + mt * 16 + quad * 4;
#pragma unroll
            for (int nt = 0; nt < 4; nt++) {
                const int vcol = nt * 16 + m16;
                uint2 pk;
                pk.x = (u32)f2bf(acc[mt][nt][0] * scl[0]) |
                       ((u32)f2bf(acc[mt][nt][1] * scl[1]) << 16);
                pk.y = (u32)f2bf(acc[mt][nt][2] * scl[2]) |
                       ((u32)f2bf(acc[mt][nt][3] * scl[3]) << 16);
                u16* dp = outN + (((size_t)bb * NHEAD + h) * KHD + vcol) * S_LEN + sbase;
                *(uint2*)dp = pk;
            }
        }
    } else {
#pragma unroll
        for (int mt = 0; mt < 4; mt++) {
#pragma unroll
            for (int r = 0; r < 4; r++) {
                const int i = row0 + wm * 64 + mt * 16 + quad * 4 + r;
                float* op = outP + (size_t)i * DMODEL + n0 + wn * 64;
#pragma unroll
                for (int nt = 0; nt < 4; nt++)
                    op[nt * 16 + m16] = acc[mt][nt][r];
            }
        }
    }
}

// ---------------------------------------------------------------------------
// Attention v6 (best measured: 48.0us). 256 q/block (64 per wave, qb=0..3),
// 64-key iters, grid (128,4): blockIdx.x = bh -> all q-tiles of one head on
// ONE XCD (linear%8 = bh%8); per-XCD K/V = 16 heads x 256KB = 4MB = L2.
// Double-buffered K/V (stage(next) -> compute(cur) -> barrier). P staged
// per 32-key half in per-wave-per-qb [16q][32k] buffers. LDS = 48KB.
// Plds swizzle: 64B rows, 16B chunk ^= (m16>>1)&3 -> conflict-free b128.
// Scores = cos/8; p = exp(y/8) via quadratic Taylor; truncate-pack via
// v_perm; row-sum via ones-MFMA on packed P (exact num/denom consistency).
// Output written DIRECTLY into the wq region in [B][H][S][64] layout.
// ---------------------------------------------------------------------------
__global__ __launch_bounds__(256, 2) void attn_kernel(
    const u16* __restrict__ wq, const u16* __restrict__ wk, const u16* __restrict__ wvT,
    u16* __restrict__ Xout)     // = wq base, [B][H][S][64]
{
    __shared__ __align__(16) u16 Klds[2][64 * 64];    // [buf][key][dim], XOR chunks
    __shared__ __align__(16) u16 Vlds[2][64 * 64];    // [buf][vcol][key], XOR chunks
    __shared__ __align__(16) u16 Plds[4][4][16 * 32]; // [wave][qb][q16][key32], XOR chunks

    const int tid  = threadIdx.x;
    const int wave = tid >> 6;
    const int lane = tid & 63;
    const int m16  = lane & 15;
    const int quad = lane >> 4;
    const int bh   = blockIdx.x;        // 0..127  (XCD = bh % 8)
    const int qt   = blockIdx.y;        // 4 tiles of 256 q

    const u16* Qb = wq  + (size_t)bh * S_LEN * KHD;
    const u16* Kb = wk  + (size_t)bh * S_LEN * KHD;
    const u16* Vb = wvT + (size_t)bh * KHD * S_LEN;

    // 64 q rows per wave: row = qr0 + qb*16 + m16
    const int qr0 = qt * 256 + wave * 64;
    short8 qf[4][2];
#pragma unroll
    for (int qb = 0; qb < 4; qb++) {
        qf[qb][0] = *(const short8*)(Qb + (size_t)(qr0 + qb * 16 + m16) * KHD + quad * 8);
        qf[qb][1] = *(const short8*)(Qb + (size_t)(qr0 + qb * 16 + m16) * KHD + 32 + quad * 8);
    }

    short8 ones;
#pragma unroll
    for (int j = 0; j < 8; j++) ones[j] = (short)0x3F80;   // bf16 1.0

    f32x4 o[4][4] = {};   // [qb][vt]: D[m=vcol][n=q]
    f32x4 ls[4]   = {};   // [qb] ones-MFMA row-sum accumulator
    const float C1 = 0.125f, C2 = 0.0078125f;   // exp(y/8) ~= 1 + y/8 + y^2/128

    const int srow   = lane >> 3;
    const int schunk = (lane & 7) ^ srow;
    const int r0     = wave * 8 + srow;
    const int pswz   = (m16 >> 1) & 3;          // Plds chunk XOR

    // prologue: stage tile 0 into buf 0
    gl_lds16(Kb + (size_t)r0 * KHD + schunk * 8,               &Klds[0][(wave * 8) * 64]);
    gl_lds16(Kb + (size_t)(r0 + 32) * KHD + schunk * 8,        &Klds[0][(wave * 8 + 32) * 64]);
    gl_lds16(Vb + (size_t)r0 * S_LEN + schunk * 8,             &Vlds[0][(wave * 8) * 64]);
    gl_lds16(Vb + (size_t)(r0 + 32) * S_LEN + schunk * 8,      &Vlds[0][(wave * 8 + 32) * 64]);
    __syncthreads();

    for (int it = 0; it < S_LEN / 64; it++) {
        const int cur = it & 1;

        // stage NEXT tile into the other buffer; latency hides under compute
        if (it + 1 < S_LEN / 64) {
            const int nxt = cur ^ 1;
            const int kt0 = (it + 1) * 64;
            gl_lds16(Kb + (size_t)(kt0 + r0) * KHD + schunk * 8,        &Klds[nxt][(wave * 8) * 64]);
            gl_lds16(Kb + (size_t)(kt0 + r0 + 32) * KHD + schunk * 8,   &Klds[nxt][(wave * 8 + 32) * 64]);
            gl_lds16(Vb + (size_t)r0 * S_LEN + kt0 + schunk * 8,        &Vlds[nxt][(wave * 8) * 64]);
            gl_lds16(Vb + (size_t)(r0 + 32) * S_LEN + kt0 + schunk * 8, &Vlds[nxt][(wave * 8 + 32) * 64]);
        }

#pragma unroll
        for (int cc = 0; cc < 2; cc++) {
            // S^T for keys cc*32..cc*32+31: D[m=key][n=q] = K x Q^T
#pragma unroll
            for (int mm = 0; mm < 2; mm++) {
                const int mt = cc * 2 + mm;
                const short8 kf0 = *(const short8*)&Klds[cur][(mt * 16 + m16) * 64 + (quad ^ (m16 & 7)) * 8];
                const short8 kf1 = *(const short8*)&Klds[cur][(mt * 16 + m16) * 64 + ((4 + quad) ^ (m16 & 7)) * 8];
#pragma unroll
                for (int qb = 0; qb < 4; qb++) {
                    f32x4 s = {};
                    s = __builtin_amdgcn_mfma_f32_16x16x32_bf16(kf0, qf[qb][0], s, 0, 0, 0);
                    s = __builtin_amdgcn_mfma_f32_16x16x32_bf16(kf1, qf[qb][1], s, 0, 0, 0);
                    u32 up[4];
#pragma unroll
                    for (int r = 0; r < 4; r++) {
                        const float y = s[r];
                        const float p = fmaf(fmaf(C2, y, C1), y, 1.0f);
                        up[r] = __float_as_uint(p);
                    }
                    uint2 pk;   // truncation-pack two bf16 per u32 via byte-perm
                    pk.x = __builtin_amdgcn_perm(up[1], up[0], 0x07060302u);
                    pk.y = __builtin_amdgcn_perm(up[3], up[2], 0x07060302u);
                    // logical: row m16 (64B), chunk = mm*2 + quad>>1, half = quad&1
                    *(uint2*)((char*)&Plds[wave][qb][0] + m16 * 64 +
                              ((((mm << 1) + (quad >> 1)) ^ pswz) << 4) + ((quad & 1) << 3)) = pk;
                }
            }

            // PV for this 32-key half + ones-MFMA row-sum (wave-private P)
            short8 vfr[4];
#pragma unroll
            for (int vt = 0; vt < 4; vt++)
                vfr[vt] = *(const short8*)&Vlds[cur][(vt * 16 + m16) * 64 +
                                                     (((cc << 2) + quad) ^ (m16 & 7)) * 8];
            __builtin_amdgcn_s_setprio(1);
#pragma unroll
            for (int qb = 0; qb < 4; qb++) {
                const short8 pb = *(const short8*)((const char*)&Plds[wave][qb][0] + m16 * 64 +
                                                   ((quad ^ pswz) << 4));
                ls[qb] = __builtin_amdgcn_mfma_f32_16x16x32_bf16(ones, pb, ls[qb], 0, 0, 0);
#pragma unroll
                for (int vt = 0; vt < 4; vt++)
                    o[qb][vt] = __builtin_amdgcn_mfma_f32_16x16x32_bf16(vfr[vt], pb, o[qb][vt], 0, 0, 0);
            }
            __builtin_amdgcn_s_setprio(0);
        }

        __syncthreads();   // drains vmcnt (next tile visible) + frees cur buf
    }

    // epilogue: lane's q = m16; write into wq region, [B][H][S][64] layout.
    u16* outB = Xout + (size_t)bh * S_LEN * KHD;
#pragma unroll
    for (int qb = 0; qb < 4; qb++) {
        const float inv = 1.0f / ls[qb][0];
        const int qrow = qr0 + qb * 16 + m16;
        u16* cp = outB + (size_t)qrow * KHD;
#pragma unroll
        for (int vt = 0; vt < 4; vt++) {
            uint2 pk;
            pk.x = (u32)f2bf(o[qb][vt][0] * inv) | ((u32)f2bf(o[qb][vt][1] * inv) << 16);
            pk.y = (u32)f2bf(o[qb][vt][2] * inv) | ((u32)f2bf(o[qb][vt][3] * inv) << 16);
            *(uint2*)(cp + vt * 16 + quad * 4) = pk;
        }
    }
}

extern "C" void kernel_launch(void* const* d_in, const int* in_sizes, int n_in,
                              void* d_out, int out_size, void* d_ws, size_t ws_size,
                              hipStream_t stream) {
    const float* q    = (const float*)d_in[0];
    const float* k    = (const float*)d_in[1];
    const float* v    = (const float*)d_in[2];
    const float* WQ   = (const float*)d_in[3];
    const float* WK   = (const float*)d_in[4];
    const float* WV   = (const float*)d_in[5];
    const float* Wout = (const float*)d_in[6];
    float* out = (float*)d_out;

    // ws: [3][B*H*S*64] bf16 (wq, wk, wvT) 50.3 MB + [4][512*512] bf16 2 MB
    const size_t per = (size_t)BATCH * NHEAD * S_LEN * KHD;
    u16* wsQKV = (u16*)d_ws;
    u16* wsW   = wsQKV + 3 * per;

    // 1. weights -> bf16
    wcvt_kernel<<<dim3(256, 4), 256, 0, stream>>>(WQ, WK, WV, Wout, wsW);

    // 2. q,k projections + norm (fused fp32->bf16 A staging) -> wq, wk
    gemm_kernel<1><<<dim3(NROW / 128, DMODEL / 128, 2), 256, 0, stream>>>(
        q, k, nullptr, wsW, wsQKV, nullptr);

    // 3. v projection + norm (fused) -> transposed wvT [B][H][64][S]
    gemm_kernel<2><<<dim3(S_LEN / 128, DMODEL / 128, BATCH), 256, 0, stream>>>(
        v, nullptr, nullptr, wsW + (size_t)2 * DMODEL * DMODEL, wsQKV + 2 * per, nullptr);

    // 4. attention -> concat written in-place into the wq region
    //    ([B][H][S][64]); each block touches only its own slice -> no race
    attn_kernel<<<dim3(BATCH * NHEAD, S_LEN / 256), 256, 0, stream>>>(
        wsQKV, wsQKV + per, wsQKV + 2 * per, wsQKV);

    // 5. output projection (A gathered from [B][H][S][64]) -> fp32 d_out
    gemm_kernel<0><<<dim3(NROW / 128, DMODEL / 128, 1), 256, 0, stream>>>(
        nullptr, nullptr, wsQKV, wsW + (size_t)3 * DMODEL * DMODEL, nullptr, out);
}

// Round 7
// 238.867 us; speedup vs baseline: 1.0120x; 1.0120x over previous
//
#include <hip/hip_runtime.h>
#include <cstdint>
#include <cstddef>

typedef unsigned int u32;
typedef unsigned short u16;
typedef __attribute__((ext_vector_type(8))) short short8;   // 8 bf16 = 4 VGPRs (MFMA A/B frag)
typedef __attribute__((ext_vector_type(4))) float f32x4;    // MFMA C/D frag

#define S_LEN 1024
#define BATCH 16
#define NHEAD 8
#define DMODEL 512
#define KHD 64
#define NROW (S_LEN * BATCH)          // 16384 GEMM rows

__device__ __forceinline__ u16 f2bf(float f) {
    u32 u = __float_as_uint(f);
    return (u16)((u + 0x7fffu + ((u >> 16) & 1u)) >> 16);   // RTNE
}

__device__ __forceinline__ void gl_lds16(const void* g, void* l) {
    __builtin_amdgcn_global_load_lds(
        (const __attribute__((address_space(1))) void*)(uintptr_t)g,
        (__attribute__((address_space(3))) void*)(uintptr_t)l, 16, 0, 0);
}

// ---------------------------------------------------------------------------
// Weights fp32 -> bf16, packed [4][512*512] into ws.
// ---------------------------------------------------------------------------
__global__ __launch_bounds__(256) void wcvt_kernel(
    const float* __restrict__ WQ, const float* __restrict__ WK,
    const float* __restrict__ WV, const float* __restrict__ Wo,
    u16* __restrict__ dst)
{
    const int m = blockIdx.y;
    const float* __restrict__ src = (m == 0) ? WQ : (m == 1) ? WK : (m == 2) ? WV : Wo;
    const int idx = (blockIdx.x * 256 + threadIdx.x) * 4;
    const float4 v = *(const float4*)(src + idx);
    u16 r[4];
    r[0] = f2bf(v.x); r[1] = f2bf(v.y); r[2] = f2bf(v.z); r[3] = f2bf(v.w);
    *(uint2*)(dst + (size_t)m * DMODEL * DMODEL + idx) = *(uint2*)r;
}

// ---------------------------------------------------------------------------
// Projection GEMMs (M=1: q/k; M=2: v). R5 structure (single 32KB buffers,
// stage -> sync -> compute -> sync) -- R6's dbuf for these was a ~2us net
// regression (occupancy loss), reverted.
// FUSED fp32->bf16 A staging: global_load_dwordx4 + v_cvt_pk_bf16_f32 +
// swizzled ds_write into the same Alds layout the K-loop reads.
// M==1: per-head L2 norm, bf16 out [B][H][S][64], z=q/k.  grid (128,4,2)
// M==2: per-head L2 norm, V transposed out [B][H][64][S]. grid (8,4,16)
// ---------------------------------------------------------------------------
template<int M>
__global__ __launch_bounds__(256) void gemm_kernel(
    const float* __restrict__ A0,   // fp32 activation (M1: q; M2: v)
    const float* __restrict__ A1,   // fp32 activation (M1: k)
    const u16* __restrict__ Wb,     // bf16 weight panel (M1: +z*D*D inside)
    u16* __restrict__ outN)
{
    __shared__ __align__(16) u16 Alds[128 * 64];
    __shared__ __align__(16) u16 Blds[128 * 64];

    const int tid  = threadIdx.x;
    const int wave = tid >> 6;
    const int lane = tid & 63;
    const int m16  = lane & 15;
    const int quad = lane >> 4;
    const int wm   = wave >> 1;
    const int wn   = wave & 1;
    const int n0   = blockIdx.y * 128;
    const int row0 = blockIdx.x * 128;
    const int z    = (M == 1) ? blockIdx.z : 0;
    const int bb   = (M == 2) ? blockIdx.z : 0;

    const float* __restrict__ A32 =
        (M == 1) ? (z ? A1 : A0) : (A0 + (size_t)bb * DMODEL);
    const size_t astr = (M == 2) ? (size_t)BATCH * DMODEL : (size_t)DMODEL;
    const u16* __restrict__ B = Wb + ((M == 1) ? (size_t)z * DMODEL * DMODEL : 0);

    f32x4 acc[4][4] = {};

    const int brow   = lane >> 3;              // 0..7
    const int bchunk = (lane & 7) ^ brow;      // XOR chunk swizzle (B)
    const int acf    = lane & 7;               // fused path: 16B fp32 chunk

    for (int kt = 0; kt < DMODEL; kt += 64) {
        __syncthreads();   // previous-iteration frag reads done
        {
            const u16* bp = B + (size_t)(n0 + wave * 32 + brow) * DMODEL + kt + bchunk * 8;
            u16* lb = &Blds[(wave * 32) * 64];
            float4 av[8];
#pragma unroll
            for (int j = 0; j < 8; j++) {
                const int rl = wave * 32 + (j & 3) * 8 + brow;
                const int cf = (j >> 2) * 8 + acf;        // 0..15
                av[j] = *(const float4*)(A32 + (size_t)(row0 + rl) * astr + kt + cf * 4);
            }
#pragma unroll
            for (int j = 0; j < 4; j++)
                gl_lds16(bp + (size_t)j * 8 * DMODEL, lb + j * 8 * 64);
#pragma unroll
            for (int j = 0; j < 8; j++) {
                const int rl = wave * 32 + (j & 3) * 8 + brow;
                const int cf = (j >> 2) * 8 + acf;
                u32 lo, hi;
                asm("v_cvt_pk_bf16_f32 %0, %1, %2" : "=v"(lo) : "v"(av[j].x), "v"(av[j].y));
                asm("v_cvt_pk_bf16_f32 %0, %1, %2" : "=v"(hi) : "v"(av[j].z), "v"(av[j].w));
                uint2 pk; pk.x = lo; pk.y = hi;
                // bf16 LDS layout: row rl, chunk (cf>>1)^(rl&7), half cf&1
                *(uint2*)&Alds[rl * 64 + (((cf >> 1) ^ (rl & 7)) << 3) + ((cf & 1) << 2)] = pk;
            }
        }
        __syncthreads();   // tiles visible

#pragma unroll
        for (int half = 0; half < 2; half++) {
            short8 af[4], bfr[4];
#pragma unroll
            for (int mt = 0; mt < 4; mt++)
                af[mt] = *(const short8*)&Alds[(wm * 64 + mt * 16 + m16) * 64 +
                                               (((half << 2) + quad) ^ (m16 & 7)) * 8];
#pragma unroll
            for (int nt = 0; nt < 4; nt++)
                bfr[nt] = *(const short8*)&Blds[(wn * 64 + nt * 16 + m16) * 64 +
                                                (((half << 2) + quad) ^ (m16 & 7)) * 8];
#pragma unroll
            for (int mt = 0; mt < 4; mt++)
#pragma unroll
                for (int nt = 0; nt < 4; nt++)
                    acc[mt][nt] = __builtin_amdgcn_mfma_f32_16x16x32_bf16(af[mt], bfr[nt], acc[mt][nt], 0, 0, 0);
        }
    }

    if (M == 1) {
        const int h = (n0 >> 6) + wn;
        u16* outZ = outN + (size_t)z * BATCH * NHEAD * S_LEN * KHD;
#pragma unroll
        for (int mt = 0; mt < 4; mt++) {
#pragma unroll
            for (int r = 0; r < 4; r++) {
                float ss = 0.0f;
#pragma unroll
                for (int nt = 0; nt < 4; nt++) ss += acc[mt][nt][r] * acc[mt][nt][r];
                ss += __shfl_xor(ss, 1);
                ss += __shfl_xor(ss, 2);
                ss += __shfl_xor(ss, 4);
                ss += __shfl_xor(ss, 8);
                const float sc = 1.0f / fmaxf(sqrtf(ss), 1e-12f);
                const int i = row0 + wm * 64 + mt * 16 + quad * 4 + r;
                const int s = i >> 4, b = i & 15;
                u16* op = outN + (size_t)z * BATCH * NHEAD * S_LEN * KHD +
                          (((size_t)b * NHEAD + h) * S_LEN + s) * KHD;
                (void)outZ;
#pragma unroll
                for (int nt = 0; nt < 4; nt++)
                    op[nt * 16 + m16] = f2bf(acc[mt][nt][r] * sc);
            }
        }
    } else {
        const int h = (n0 >> 6) + wn;
#pragma unroll
        for (int mt = 0; mt < 4; mt++) {
            float scl[4];
#pragma unroll
            for (int r = 0; r < 4; r++) {
                float ss = 0.0f;
#pragma unroll
                for (int nt = 0; nt < 4; nt++) ss += acc[mt][nt][r] * acc[mt][nt][r];
                ss += __shfl_xor(ss, 1);
                ss += __shfl_xor(ss, 2);
                ss += __shfl_xor(ss, 4);
                ss += __shfl_xor(ss, 8);
                scl[r] = 1.0f / fmaxf(sqrtf(ss), 1e-12f);
            }
            const int sbase = row0 + wm * 64 + mt * 16 + quad * 4;
#pragma unroll
            for (int nt = 0; nt < 4; nt++) {
                const int vcol = nt * 16 + m16;
                uint2 pk;
                pk.x = (u32)f2bf(acc[mt][nt][0] * scl[0]) |
                       ((u32)f2bf(acc[mt][nt][1] * scl[1]) << 16);
                pk.y = (u32)f2bf(acc[mt][nt][2] * scl[2]) |
                       ((u32)f2bf(acc[mt][nt][3] * scl[3]) << 16);
                u16* dp = outN + (((size_t)bb * NHEAD + h) * KHD + vcol) * S_LEN + sbase;
                *(uint2*)dp = pk;
            }
        }
    }
}

// ---------------------------------------------------------------------------
// Output projection, dedicated kernel. R6 post-mortem: 65.7us flat across two
// structural changes, all pipes <15%, 8 waves/CU -> latency-starved. Fixes:
//  * 512 threads (8 waves) per 128x128 block -> 16 waves/CU (2 blocks x 8).
//  * T4 counted-vmcnt pipeline (m201 pattern): 2-deep prologue; per iter
//    compute -> s_barrier -> stage(t+2) -> s_waitcnt vmcnt(4) -> s_barrier.
//    Loads never drained to 0 in steady state; pure global_load_lds path.
// A gathered from [B][H][S][64] (attn concat); B = Wout panel. fp32 out.
// grid (128,4) x 512 threads.
// ---------------------------------------------------------------------------
__global__ __launch_bounds__(512, 2) void gemm_out_kernel(
    const u16* __restrict__ Abf,    // bf16 A, [B][H][S][64]
    const u16* __restrict__ Wb,     // bf16 Wout [512][512]
    float* __restrict__ outP)
{
    __shared__ __align__(16) u16 Alds[2][128 * 64];
    __shared__ __align__(16) u16 Blds[2][128 * 64];

    const int tid  = threadIdx.x;
    const int wave = tid >> 6;          // 0..7
    const int lane = tid & 63;
    const int m16  = lane & 15;
    const int quad = lane >> 4;
    const int wm   = wave >> 1;         // 0..3: 32-row group
    const int wn   = wave & 1;          // 0..1: 64-col half
    const int n0   = blockIdx.y * 128;
    const int row0 = blockIdx.x * 128;

    const int brow   = lane >> 3;              // 0..7
    const int bchunk = (lane & 7) ^ brow;      // XOR chunk swizzle

    f32x4 acc[2][4] = {};

    auto stage = [&](int kt, int b) {
        // A: 16 rows/wave from [B][H][S][64]; per K-step all cols in head kt/64
        const int colc = kt + bchunk * 8;
        const int hh   = colc >> 6;
        const int kk   = colc & 63;
        u16* la = &Alds[b][(wave * 16) * 64];
#pragma unroll
        for (int j = 0; j < 2; j++) {
            const int i  = row0 + wave * 16 + j * 8 + brow;
            const int ss = i >> 4, bx = i & 15;
            gl_lds16(Abf + (((size_t)(bx * NHEAD + hh) * S_LEN + ss) * KHD + kk),
                     la + j * 8 * 64);
        }
        const u16* bp = Wb + (size_t)(n0 + wave * 16 + brow) * DMODEL + kt + bchunk * 8;
        u16* lb = &Blds[b][(wave * 16) * 64];
#pragma unroll
        for (int j = 0; j < 2; j++)
            gl_lds16(bp + (size_t)j * 8 * DMODEL, lb + j * 8 * 64);
    };
    auto compute = [&](int b) {
#pragma unroll
        for (int half = 0; half < 2; half++) {
            short8 af[2], bfr[4];
#pragma unroll
            for (int mt = 0; mt < 2; mt++)
                af[mt] = *(const short8*)&Alds[b][(wm * 32 + mt * 16 + m16) * 64 +
                                                  (((half << 2) + quad) ^ (m16 & 7)) * 8];
#pragma unroll
            for (int nt = 0; nt < 4; nt++)
                bfr[nt] = *(const short8*)&Blds[b][(wn * 64 + nt * 16 + m16) * 64 +
                                                   (((half << 2) + quad) ^ (m16 & 7)) * 8];
#pragma unroll
            for (int mt = 0; mt < 2; mt++)
#pragma unroll
                for (int nt = 0; nt < 4; nt++)
                    acc[mt][nt] = __builtin_amdgcn_mfma_f32_16x16x32_bf16(af[mt], bfr[nt], acc[mt][nt], 0, 0, 0);
        }
    };

    // prologue: 2-deep prefetch (4 loads per wave per tile)
    stage(0, 0);
    stage(64, 1);
    asm volatile("s_waitcnt vmcnt(4)" ::: "memory");   // tile 0 done (tile 1 in flight)
    __builtin_amdgcn_s_barrier();
    __builtin_amdgcn_sched_barrier(0);

#pragma unroll
    for (int t = 0; t < 8; t++) {
        compute(t & 1);
        if (t < 6) {
            __builtin_amdgcn_s_barrier();              // readers done with buf t&1
            __builtin_amdgcn_sched_barrier(0);
            stage((t + 2) * 64, t & 1);                // 4 loads
        }
        if (t < 7) {
            if (t < 6) asm volatile("s_waitcnt vmcnt(4)" ::: "memory");
            else       asm volatile("s_waitcnt vmcnt(0)" ::: "memory");
            __builtin_amdgcn_s_barrier();              // buf (t+1)&1 published
            __builtin_amdgcn_sched_barrier(0);
        }
    }

    // epilogue: fp32 C write
#pragma unroll
    for (int mt = 0; mt < 2; mt++) {
#pragma unroll
        for (int r = 0; r < 4; r++) {
            const int i = row0 + wm * 32 + mt * 16 + quad * 4 + r;
            float* op = outP + (size_t)i * DMODEL + n0 + wn * 64;
#pragma unroll
            for (int nt = 0; nt < 4; nt++)
                op[nt * 16 + m16] = acc[mt][nt][r];
        }
    }
}

// ---------------------------------------------------------------------------
// Attention v6 (best measured: 48.0us). 256 q/block (64 per wave, qb=0..3),
// 64-key iters, grid (128,4): blockIdx.x = bh -> all q-tiles of one head on
// ONE XCD (linear%8 = bh%8); per-XCD K/V = 16 heads x 256KB = 4MB = L2.
// Double-buffered K/V (stage(next) -> compute(cur) -> barrier). P staged
// per 32-key half in per-wave-per-qb [16q][32k] buffers. LDS = 48KB.
// Plds swizzle: 64B rows, 16B chunk ^= (m16>>1)&3 -> conflict-free b128.
// Scores = cos/8; p = exp(y/8) via quadratic Taylor; truncate-pack via
// v_perm; row-sum via ones-MFMA on packed P (exact num/denom consistency).
// Output written DIRECTLY into the wq region in [B][H][S][64] layout.
// ---------------------------------------------------------------------------
__global__ __launch_bounds__(256, 2) void attn_kernel(
    const u16* __restrict__ wq, const u16* __restrict__ wk, const u16* __restrict__ wvT,
    u16* __restrict__ Xout)     // = wq base, [B][H][S][64]
{
    __shared__ __align__(16) u16 Klds[2][64 * 64];    // [buf][key][dim], XOR chunks
    __shared__ __align__(16) u16 Vlds[2][64 * 64];    // [buf][vcol][key], XOR chunks
    __shared__ __align__(16) u16 Plds[4][4][16 * 32]; // [wave][qb][q16][key32], XOR chunks

    const int tid  = threadIdx.x;
    const int wave = tid >> 6;
    const int lane = tid & 63;
    const int m16  = lane & 15;
    const int quad = lane >> 4;
    const int bh   = blockIdx.x;        // 0..127  (XCD = bh % 8)
    const int qt   = blockIdx.y;        // 4 tiles of 256 q

    const u16* Qb = wq  + (size_t)bh * S_LEN * KHD;
    const u16* Kb = wk  + (size_t)bh * S_LEN * KHD;
    const u16* Vb = wvT + (size_t)bh * KHD * S_LEN;

    // 64 q rows per wave: row = qr0 + qb*16 + m16
    const int qr0 = qt * 256 + wave * 64;
    short8 qf[4][2];
#pragma unroll
    for (int qb = 0; qb < 4; qb++) {
        qf[qb][0] = *(const short8*)(Qb + (size_t)(qr0 + qb * 16 + m16) * KHD + quad * 8);
        qf[qb][1] = *(const short8*)(Qb + (size_t)(qr0 + qb * 16 + m16) * KHD + 32 + quad * 8);
    }

    short8 ones;
#pragma unroll
    for (int j = 0; j < 8; j++) ones[j] = (short)0x3F80;   // bf16 1.0

    f32x4 o[4][4] = {};   // [qb][vt]: D[m=vcol][n=q]
    f32x4 ls[4]   = {};   // [qb] ones-MFMA row-sum accumulator
    const float C1 = 0.125f, C2 = 0.0078125f;   // exp(y/8) ~= 1 + y/8 + y^2/128

    const int srow   = lane >> 3;
    const int schunk = (lane & 7) ^ srow;
    const int r0     = wave * 8 + srow;
    const int pswz   = (m16 >> 1) & 3;          // Plds chunk XOR

    // prologue: stage tile 0 into buf 0
    gl_lds16(Kb + (size_t)r0 * KHD + schunk * 8,               &Klds[0][(wave * 8) * 64]);
    gl_lds16(Kb + (size_t)(r0 + 32) * KHD + schunk * 8,        &Klds[0][(wave * 8 + 32) * 64]);
    gl_lds16(Vb + (size_t)r0 * S_LEN + schunk * 8,             &Vlds[0][(wave * 8) * 64]);
    gl_lds16(Vb + (size_t)(r0 + 32) * S_LEN + schunk * 8,      &Vlds[0][(wave * 8 + 32) * 64]);
    __syncthreads();

    for (int it = 0; it < S_LEN / 64; it++) {
        const int cur = it & 1;

        // stage NEXT tile into the other buffer; latency hides under compute
        if (it + 1 < S_LEN / 64) {
            const int nxt = cur ^ 1;
            const int kt0 = (it + 1) * 64;
            gl_lds16(Kb + (size_t)(kt0 + r0) * KHD + schunk * 8,        &Klds[nxt][(wave * 8) * 64]);
            gl_lds16(Kb + (size_t)(kt0 + r0 + 32) * KHD + schunk * 8,   &Klds[nxt][(wave * 8 + 32) * 64]);
            gl_lds16(Vb + (size_t)r0 * S_LEN + kt0 + schunk * 8,        &Vlds[nxt][(wave * 8) * 64]);
            gl_lds16(Vb + (size_t)(r0 + 32) * S_LEN + kt0 + schunk * 8, &Vlds[nxt][(wave * 8 + 32) * 64]);
        }

#pragma unroll
        for (int cc = 0; cc < 2; cc++) {
            // S^T for keys cc*32..cc*32+31: D[m=key][n=q] = K x Q^T
#pragma unroll
            for (int mm = 0; mm < 2; mm++) {
                const int mt = cc * 2 + mm;
                const short8 kf0 = *(const short8*)&Klds[cur][(mt * 16 + m16) * 64 + (quad ^ (m16 & 7)) * 8];
                const short8 kf1 = *(const short8*)&Klds[cur][(mt * 16 + m16) * 64 + ((4 + quad) ^ (m16 & 7)) * 8];
#pragma unroll
                for (int qb = 0; qb < 4; qb++) {
                    f32x4 s = {};
                    s = __builtin_amdgcn_mfma_f32_16x16x32_bf16(kf0, qf[qb][0], s, 0, 0, 0);
                    s = __builtin_amdgcn_mfma_f32_16x16x32_bf16(kf1, qf[qb][1], s, 0, 0, 0);
                    u32 up[4];
#pragma unroll
                    for (int r = 0; r < 4; r++) {
                        const float y = s[r];
                        const float p = fmaf(fmaf(C2, y, C1), y, 1.0f);
                        up[r] = __float_as_uint(p);
                    }
                    uint2 pk;   // truncation-pack two bf16 per u32 via byte-perm
                    pk.x = __builtin_amdgcn_perm(up[1], up[0], 0x07060302u);
                    pk.y = __builtin_amdgcn_perm(up[3], up[2], 0x07060302u);
                    // logical: row m16 (64B), chunk = mm*2 + quad>>1, half = quad&1
                    *(uint2*)((char*)&Plds[wave][qb][0] + m16 * 64 +
                              ((((mm << 1) + (quad >> 1)) ^ pswz) << 4) + ((quad & 1) << 3)) = pk;
                }
            }

            // PV for this 32-key half + ones-MFMA row-sum (wave-private P)
            short8 vfr[4];
#pragma unroll
            for (int vt = 0; vt < 4; vt++)
                vfr[vt] = *(const short8*)&Vlds[cur][(vt * 16 + m16) * 64 +
                                                     (((cc << 2) + quad) ^ (m16 & 7)) * 8];
            __builtin_amdgcn_s_setprio(1);
#pragma unroll
            for (int qb = 0; qb < 4; qb++) {
                const short8 pb = *(const short8*)((const char*)&Plds[wave][qb][0] + m16 * 64 +
                                                   ((quad ^ pswz) << 4));
                ls[qb] = __builtin_amdgcn_mfma_f32_16x16x32_bf16(ones, pb, ls[qb], 0, 0, 0);
#pragma unroll
                for (int vt = 0; vt < 4; vt++)
                    o[qb][vt] = __builtin_amdgcn_mfma_f32_16x16x32_bf16(vfr[vt], pb, o[qb][vt], 0, 0, 0);
            }
            __builtin_amdgcn_s_setprio(0);
        }

        __syncthreads();   // drains vmcnt (next tile visible) + frees cur buf
    }

    // epilogue: lane's q = m16; write into wq region, [B][H][S][64] layout.
    u16* outB = Xout + (size_t)bh * S_LEN * KHD;
#pragma unroll
    for (int qb = 0; qb < 4; qb++) {
        const float inv = 1.0f / ls[qb][0];
        const int qrow = qr0 + qb * 16 + m16;
        u16* cp = outB + (size_t)qrow * KHD;
#pragma unroll
        for (int vt = 0; vt < 4; vt++) {
            uint2 pk;
            pk.x = (u32)f2bf(o[qb][vt][0] * inv) | ((u32)f2bf(o[qb][vt][1] * inv) << 16);
            pk.y = (u32)f2bf(o[qb][vt][2] * inv) | ((u32)f2bf(o[qb][vt][3] * inv) << 16);
            *(uint2*)(cp + vt * 16 + quad * 4) = pk;
        }
    }
}

extern "C" void kernel_launch(void* const* d_in, const int* in_sizes, int n_in,
                              void* d_out, int out_size, void* d_ws, size_t ws_size,
                              hipStream_t stream) {
    const float* q    = (const float*)d_in[0];
    const float* k    = (const float*)d_in[1];
    const float* v    = (const float*)d_in[2];
    const float* WQ   = (const float*)d_in[3];
    const float* WK   = (const float*)d_in[4];
    const float* WV   = (const float*)d_in[5];
    const float* Wout = (const float*)d_in[6];
    float* out = (float*)d_out;

    // ws: [3][B*H*S*64] bf16 (wq, wk, wvT) 50.3 MB + [4][512*512] bf16 2 MB
    const size_t per = (size_t)BATCH * NHEAD * S_LEN * KHD;
    u16* wsQKV = (u16*)d_ws;
    u16* wsW   = wsQKV + 3 * per;

    // 1. weights -> bf16
    wcvt_kernel<<<dim3(256, 4), 256, 0, stream>>>(WQ, WK, WV, Wout, wsW);

    // 2. q,k projections + norm (fused fp32->bf16 A staging) -> wq, wk
    gemm_kernel<1><<<dim3(NROW / 128, DMODEL / 128, 2), 256, 0, stream>>>(
        q, k, wsW, wsQKV);

    // 3. v projection + norm (fused) -> transposed wvT [B][H][64][S]
    gemm_kernel<2><<<dim3(S_LEN / 128, DMODEL / 128, BATCH), 256, 0, stream>>>(
        v, nullptr, wsW + (size_t)2 * DMODEL * DMODEL, wsQKV + 2 * per);

    // 4. attention -> concat written in-place into the wq region
    //    ([B][H][S][64]); each block touches only its own slice -> no race
    attn_kernel<<<dim3(BATCH * NHEAD, S_LEN / 256), 256, 0, stream>>>(
        wsQKV, wsQKV + per, wsQKV + 2 * per, wsQKV);

    // 5. output projection (8-wave blocks, counted-vmcnt pipeline) -> fp32
    gemm_out_kernel<<<dim3(NROW / 128, DMODEL / 128), 512, 0, stream>>>(
        wsQKV, wsW + (size_t)3 * DMODEL * DMODEL, out);
}